// Round 5
// baseline (179.698 us; speedup 1.0000x reference)
//
#include <hip/hip_runtime.h>
#include <math.h>

// HarmonicCQT via f16 MFMA: out[b,t,k] = |sum_n xpad[t*512+n] * (kr[k,n]+i*ki[k,n])|
//
// Path A (ws >= ~11.7MB), 3 dispatches:
//   1. prep_fused : memset(accb) + fp32 audio -> padded f16 xp + read-coalesced
//                   B-fragment pack (x4096 pre-scale, exact MFMA lane order)
//   2. cqt_mfma3  : per-wave WGs (64 thr), slab=1024 split-K, register
//                   prefetch depth 1, fire-and-forget fp32 atomics
//   3. cqt_mag_final : sqrt(re^2+im^2)
// Path B (ws >= ~7.7MB): round-3 LDS-staging MFMA kernel (verified, ~224us).
// Path C: verified fp32 kernel (~370us).
//
// MFMA 16x16x32 layouts (verified rounds 3/4, absmax 4.9e-4):
//   A[m=lane&15][k=(lane>>4)*8+j], B[k=(lane>>4)*8+j][n=lane&15],
//   C/D: col=lane&15, row=(lane>>4)*4+reg.
// bp layout per chunk (32 K-cols): 2048B = [64 lanes x 16B re][64 x 16B im],
// fragment for lane (q,m) at (q*16+m)*8 — identical to round 4 (verified).

namespace {
constexpr int kSR    = 22050;
constexpr int kHop   = 512;
constexpr int kBins  = 168;
constexpr int kT     = 689;
constexpr int kB     = 4;
constexpr int kS     = 352768;
constexpr int kTPad  = 768;     // frames padded to 12 fblocks of 64
constexpr int kBinPad = 176;    // 11 groups of 16
constexpr int kAccTotal = kB * kTPad * kBinPad * 2;   // 1,081,344 floats
constexpr float kKScale    = 4096.0f;
constexpr float kKScaleInv = 1.0f / 4096.0f;
constexpr int kMaxJobs = 96;
}

typedef _Float16 half8 __attribute__((ext_vector_type(8)));
typedef _Float16 half2v __attribute__((ext_vector_type(2)));
typedef float floatx4 __attribute__((ext_vector_type(4)));

struct Jobs {          // path B job table
  int k0[48];
  int lo[48];
  int hi[48];
  int n;
};

struct Jobs3 {         // path A job table
  int k0[kMaxJobs];    // bin-group start (multiple of 16)
  int lo[kMaxJobs];    // support start col (256-aligned)
  int nch[kMaxJobs];   // 32-col chunks in this job (even)
  int cbase[kMaxJobs]; // chunk prefix sum
  int sbase[kMaxJobs]; // span (64-col) prefix sum = cbase/2
  int n;
  int totch;
  int totsp;
};

__device__ inline void atomAddF(float* p, float v) {
  __hip_atomic_fetch_add(p, v, __ATOMIC_RELAXED, __HIP_MEMORY_SCOPE_AGENT);
}

// ---- fused prep: [0,nbx) prep_x | [nbx,nbx+nbp) bpack | rest memset ----
__global__ __launch_bounds__(256) void prep_fused(
    const float* __restrict__ x, const float* __restrict__ kr,
    const float* __restrict__ ki, _Float16* __restrict__ xp,
    _Float16* __restrict__ bp, float* __restrict__ accb,
    const int pad, const int xps, const int nmax,
    const int nbx, const int nbp, const Jobs3 jt) {
  int bid = blockIdx.x;
  const int tid = threadIdx.x;

  if (bid < nbx) {
    // --- padded f16 audio ---
    const int halfx = xps >> 1;
    const int gid = bid * 256 + tid;
    if (gid >= kB * halfx) return;
    const int b = gid / halfx;
    const int i = (gid - b * halfx) * 2;
    float v0 = 0.f, v1 = 0.f;
    if (i     >= pad && i     < pad + kS) v0 = x[(size_t)b * kS + (i - pad)];
    if (i + 1 >= pad && i + 1 < pad + kS) v1 = x[(size_t)b * kS + (i + 1 - pad)];
    half2v h; h.x = (_Float16)v0; h.y = (_Float16)v1;
    *(half2v*)&xp[(size_t)b * xps + i] = h;
    return;
  }
  bid -= nbx;

  if (bid < nbp) {
    // --- B-fragment pack, read-coalesced: wave = (spanSlot, m) ---
    const int wave = tid >> 6;
    const int l = tid & 63;
    const int spanSlot = bid >> 2;
    const int m = (bid & 3) * 4 + wave;
    if (spanSlot >= jt.totsp) return;
    int jb = 0;
    #pragma unroll 1
    for (int j = 1; j < jt.n; ++j)
      if (spanSlot >= jt.sbase[j]) jb = j;
    const int s = spanSlot - jt.sbase[jb];
    const int bin = jt.k0[jb] + m;
    const int col = jt.lo[jb] + s * 64 + l;      // lanes -> consecutive cols
    const bool ok = (bin < kBins) && (col < nmax);
    const float vr = ok ? kr[(size_t)bin * nmax + col] : 0.f;
    const float vi = ok ? ki[(size_t)bin * nmax + col] : 0.f;
    const int chunk = jt.cbase[jb] + s * 2 + (l >> 5);
    const int off = chunk * 1024 + (((l >> 3) & 3) * 16 + m) * 8 + (l & 7);
    bp[off]       = (_Float16)(vr * kKScale);
    bp[off + 512] = (_Float16)(vi * kKScale);
    return;
  }
  bid -= nbp;

  // --- zero split-K accumulator ---
  const int idx = (bid * 256 + tid) * 4;
  if (idx < kAccTotal)
    *(floatx4*)&accb[idx] = (floatx4){0.f, 0.f, 0.f, 0.f};
}

// ---- path A main: per-wave WG, prefetch-pipelined MFMA ----
__global__ __launch_bounds__(64, 4) void cqt_mfma3(
    const _Float16* __restrict__ bp, const _Float16* __restrict__ xp,
    float* __restrict__ accb, const int xps, const Jobs3 jt) {
  const int jb = blockIdx.x;
  const int fb = blockIdx.y;     // 0..11 (64 frames each)
  const int b  = blockIdx.z;
  const int lane = threadIdx.x;  // 0..63
  const int m = lane & 15;
  const int q = lane >> 4;
  const int k0 = jt.k0[jb];
  const int fbase = fb * 64;
  const int nch = jt.nch[jb];

  const _Float16* ax = xp + (size_t)b * xps +
                       (size_t)(fbase + m) * kHop + q * 8 + jt.lo[jb];
  const _Float16* bpc = bp + (size_t)jt.cbase[jb] * 1024 + lane * 8;

  floatx4 accr[4], acci[4];
  #pragma unroll
  for (int tl = 0; tl < 4; ++tl) {
    accr[tl] = (floatx4){0.f, 0.f, 0.f, 0.f};
    acci[tl] = (floatx4){0.f, 0.f, 0.f, 0.f};
  }

  // prime chunk 0
  half8 brC = *(const half8*)(bpc);
  half8 biC = *(const half8*)(bpc + 512);
  half8 aC0 = *(const half8*)(ax);
  half8 aC1 = *(const half8*)(ax + 16 * kHop);
  half8 aC2 = *(const half8*)(ax + 32 * kHop);
  half8 aC3 = *(const half8*)(ax + 48 * kHop);

  #pragma unroll 1
  for (int c = 0; c < nch; ++c) {
    // prefetch chunk c+1 (clamped; harmless re-load on last iter)
    const int cn = (c + 1 < nch) ? (c + 1) : c;
    const _Float16* bn = bpc + (size_t)cn * 1024;
    const _Float16* an = ax + cn * 32;
    const half8 brN = *(const half8*)bn;
    const half8 biN = *(const half8*)(bn + 512);
    const half8 aN0 = *(const half8*)(an);
    const half8 aN1 = *(const half8*)(an + 16 * kHop);
    const half8 aN2 = *(const half8*)(an + 32 * kHop);
    const half8 aN3 = *(const half8*)(an + 48 * kHop);

    accr[0] = __builtin_amdgcn_mfma_f32_16x16x32_f16(aC0, brC, accr[0], 0, 0, 0);
    acci[0] = __builtin_amdgcn_mfma_f32_16x16x32_f16(aC0, biC, acci[0], 0, 0, 0);
    accr[1] = __builtin_amdgcn_mfma_f32_16x16x32_f16(aC1, brC, accr[1], 0, 0, 0);
    acci[1] = __builtin_amdgcn_mfma_f32_16x16x32_f16(aC1, biC, acci[1], 0, 0, 0);
    accr[2] = __builtin_amdgcn_mfma_f32_16x16x32_f16(aC2, brC, accr[2], 0, 0, 0);
    acci[2] = __builtin_amdgcn_mfma_f32_16x16x32_f16(aC2, biC, acci[2], 0, 0, 0);
    accr[3] = __builtin_amdgcn_mfma_f32_16x16x32_f16(aC3, brC, accr[3], 0, 0, 0);
    acci[3] = __builtin_amdgcn_mfma_f32_16x16x32_f16(aC3, biC, acci[3], 0, 0, 0);

    brC = brN; biC = biN;
    aC0 = aN0; aC1 = aN1; aC2 = aN2; aC3 = aN3;
  }

  // epilogue: un-scale + split-K atomic combine (no return value -> no stall)
  #pragma unroll
  for (int tl = 0; tl < 4; ++tl) {
    #pragma unroll
    for (int r = 0; r < 4; ++r) {
      const int t = fbase + tl * 16 + q * 4 + r;
      const size_t o = (((size_t)b * kTPad + t) * kBinPad + (k0 + m)) * 2;
      atomAddF(&accb[o],     accr[tl][r] * kKScaleInv);
      atomAddF(&accb[o + 1], acci[tl][r] * kKScaleInv);
    }
  }
}

// ---- final: magnitude ----
__global__ __launch_bounds__(256) void cqt_mag_final(
    const float* __restrict__ accb, float* __restrict__ out) {
  int gid = blockIdx.x * 256 + threadIdx.x;
  if (gid >= kB * kT * kBins) return;
  const int k = gid % kBins;
  const int r = gid / kBins;
  const int t = r % kT;
  const int b = r / kT;
  const float2 v = ((const float2*)accb)[((size_t)b * kTPad + t) * kBinPad + k];
  out[gid] = sqrtf(v.x * v.x + v.y * v.y);
}

// ================= path B: round-3 LDS-staging MFMA (verified) =============
__global__ __launch_bounds__(256) void prep_x_kernel(
    const float* __restrict__ x, _Float16* __restrict__ xp,
    const int pad, const int xps) {
  const int halfx = xps >> 1;
  int gid = blockIdx.x * 256 + threadIdx.x;
  if (gid >= kB * halfx) return;
  const int b = gid / halfx;
  const int i = (gid - b * halfx) * 2;
  float v0 = 0.f, v1 = 0.f;
  if (i     >= pad && i     < pad + kS) v0 = x[(size_t)b * kS + (i - pad)];
  if (i + 1 >= pad && i + 1 < pad + kS) v1 = x[(size_t)b * kS + (i + 1 - pad)];
  half2v h; h.x = (_Float16)v0; h.y = (_Float16)v1;
  *(half2v*)&xp[(size_t)b * xps + i] = h;
}

__global__ __launch_bounds__(256) void cqt_mfma_kernel(
    const float* __restrict__ kr, const float* __restrict__ ki,
    const _Float16* __restrict__ xp, float* __restrict__ accb,
    const int nmax, const int xps, const Jobs jt) {
  __shared__ _Float16 Bs[2][16][264];
  const int jb = blockIdx.x;
  const int k0   = jt.k0[jb];
  const int n_lo = jt.lo[jb];
  const int n_hi = jt.hi[jb];
  const int b  = blockIdx.z;
  const int fb = blockIdx.y;
  const int tid  = threadIdx.x;
  const int lane = tid & 63;
  const int wave = tid >> 6;
  const int m = lane & 15;
  const int q = lane >> 4;
  const int sbin = tid >> 4;
  const int scol = tid & 15;
  const int gbin = k0 + sbin;
  const bool binok = (gbin < kBins);
  const float* rowr = kr + (size_t)gbin * nmax;
  const float* rowi = ki + (size_t)gbin * nmax;
  const int fbase = fb * 256 + wave * 64;
  const _Float16* ax =
      xp + (size_t)b * xps + (size_t)(fbase + m) * kHop + q * 8;
  floatx4 accr[4], acci[4];
  #pragma unroll
  for (int tl = 0; tl < 4; ++tl) {
    accr[tl] = (floatx4){0.f, 0.f, 0.f, 0.f};
    acci[tl] = (floatx4){0.f, 0.f, 0.f, 0.f};
  }
  for (int n0r = n_lo; n0r < n_hi; n0r += 256) {
    __syncthreads();
    #pragma unroll
    for (int c = 0; c < 16; ++c) {
      const int col = n0r + scol + c * 16;
      const bool ok = binok && (col < nmax);
      const float vr = ok ? rowr[col] : 0.f;
      const float vi = ok ? rowi[col] : 0.f;
      Bs[0][sbin][scol + c * 16] = (_Float16)(vr * kKScale);
      Bs[1][sbin][scol + c * 16] = (_Float16)(vi * kKScale);
    }
    __syncthreads();
    const _Float16* axr = ax + n0r;
    #pragma unroll
    for (int c = 0; c < 8; ++c) {
      const int ko = c * 32 + q * 8;
      const half8 br = *(const half8*)&Bs[0][m][ko];
      const half8 bi = *(const half8*)&Bs[1][m][ko];
      #pragma unroll
      for (int tl = 0; tl < 4; ++tl) {
        const half8 a = *(const half8*)(axr + tl * 16 * kHop + c * 32);
        accr[tl] = __builtin_amdgcn_mfma_f32_16x16x32_f16(a, br, accr[tl], 0, 0, 0);
        acci[tl] = __builtin_amdgcn_mfma_f32_16x16x32_f16(a, bi, acci[tl], 0, 0, 0);
      }
    }
  }
  #pragma unroll
  for (int tl = 0; tl < 4; ++tl) {
    #pragma unroll
    for (int r = 0; r < 4; ++r) {
      const int t = fbase + tl * 16 + q * 4 + r;
      const size_t o = (((size_t)b * kTPad + t) * kBinPad + (k0 + m)) * 2;
      atomAddF(&accb[o],     accr[tl][r] * kKScaleInv);
      atomAddF(&accb[o + 1], acci[tl][r] * kKScaleInv);
    }
  }
}

// ================= path C: verified fp32 kernel (round 2) ==================
namespace fb32 {
constexpr int TT = 8;
constexpr int KG = 4;
constexpr int kTTiles  = (kT + TT - 1) / TT;
constexpr int kKGroups = kBins / KG;
constexpr int kWaves   = kB * kTTiles * kKGroups;
}

__global__ __launch_bounds__(256) void cqt_mag_kernel(
    const float* __restrict__ x,
    const float* __restrict__ kr,
    const float* __restrict__ ki,
    float* __restrict__ out,
    const int nmax, const int pad) {
  using namespace fb32;
  const int wave = (blockIdx.x << 2) + (threadIdx.x >> 6);
  const int lane = threadIdx.x & 63;
  if (wave >= kWaves) return;
  const int kg    = wave / (kB * kTTiles);
  const int rem   = wave - kg * (kB * kTTiles);
  const int b     = rem / kTTiles;
  const int ttile = rem - b * kTTiles;
  const int k0 = kg * KG;
  const int t0 = ttile * TT;
  const double Q  = 1.0 / (exp2(1.0 / 24.0) - 1.0);
  const double f0 = 32.7 * exp2((double)k0 / 24.0);
  int N = (int)ceil(Q * (double)kSR / f0) + 8;
  int full_start = nmax - N;
  if (full_start < 0) full_start = 0;
  int tbase[TT], lo[TT], t_last;
  { int t = t0 + TT - 1; if (t > kT - 1) t = kT - 1; t_last = t; }
  #pragma unroll
  for (int tt = 0; tt < TT; ++tt) {
    int t = t0 + tt; if (t > kT - 1) t = kT - 1;
    tbase[tt] = b * kS + t * kHop - pad;
    lo[tt]    = pad - t * kHop;
  }
  int head_start = pad - t_last * kHop;
  if (head_start < full_start) head_start = full_start;
  int safe = pad - t0 * kHop;
  if (safe < head_start) safe = head_start;
  int body_start = nmax - ((nmax - safe) & ~63);
  float accr[TT][KG], acci[TT][KG];
  #pragma unroll
  for (int tt = 0; tt < TT; ++tt)
    #pragma unroll
    for (int kk = 0; kk < KG; ++kk) { accr[tt][kk] = 0.f; acci[tt][kk] = 0.f; }
  for (int n = body_start - 64; n > head_start - 64; n -= 64) {
    const int nn = n + lane;
    const bool kok = (nn >= 0);
    float krv[KG], kiv[KG];
    #pragma unroll
    for (int kk = 0; kk < KG; ++kk) {
      krv[kk] = kok ? kr[(k0 + kk) * nmax + nn] : 0.f;
      kiv[kk] = kok ? ki[(k0 + kk) * nmax + nn] : 0.f;
    }
    float a[TT];
    #pragma unroll
    for (int tt = 0; tt < TT; ++tt)
      a[tt] = (nn >= lo[tt]) ? x[tbase[tt] + nn] : 0.f;
    #pragma unroll
    for (int tt = 0; tt < TT; ++tt)
      #pragma unroll
      for (int kk = 0; kk < KG; ++kk) {
        accr[tt][kk] = fmaf(a[tt], krv[kk], accr[tt][kk]);
        acci[tt][kk] = fmaf(a[tt], kiv[kk], acci[tt][kk]);
      }
  }
  for (int n = body_start; n < nmax; n += 64) {
    const int nn = n + lane;
    float krv[KG], kiv[KG];
    #pragma unroll
    for (int kk = 0; kk < KG; ++kk) {
      krv[kk] = kr[(k0 + kk) * nmax + nn];
      kiv[kk] = ki[(k0 + kk) * nmax + nn];
    }
    float a[TT];
    #pragma unroll
    for (int tt = 0; tt < TT; ++tt)
      a[tt] = x[tbase[tt] + nn];
    #pragma unroll
    for (int tt = 0; tt < TT; ++tt)
      #pragma unroll
      for (int kk = 0; kk < KG; ++kk) {
        accr[tt][kk] = fmaf(a[tt], krv[kk], accr[tt][kk]);
        acci[tt][kk] = fmaf(a[tt], kiv[kk], acci[tt][kk]);
      }
  }
  #pragma unroll
  for (int tt = 0; tt < TT; ++tt) {
    #pragma unroll
    for (int kk = 0; kk < KG; ++kk) {
      float r = accr[tt][kk];
      float i = acci[tt][kk];
      #pragma unroll
      for (int s = 32; s > 0; s >>= 1) {
        r += __shfl_xor(r, s, 64);
        i += __shfl_xor(i, s, 64);
      }
      if (lane == 0) {
        const int t = t0 + tt;
        if (t < kT)
          out[(b * kT + t) * kBins + (k0 + kk)] = sqrtf(r * r + i * i);
      }
    }
  }
}
// ============================================================================

extern "C" void kernel_launch(void* const* d_in, const int* in_sizes, int n_in,
                              void* d_out, int out_size, void* d_ws, size_t ws_size,
                              hipStream_t stream) {
  const float* x  = (const float*)d_in[0];   // [4, 1, 352768]
  const float* kr = (const float*)d_in[1];   // [168, nmax]
  const float* ki = (const float*)d_in[2];   // [168, nmax]
  float* out = (float*)d_out;                // [4, 1, 689, 168]

  const int nmax = in_sizes[1] / kBins;      // 23013 (runtime truth)
  const int pad  = nmax - kHop;

  const int kcap = ((nmax + 255) / 256) * 256;              // 23040
  const int xps  = (kTPad - 1) * kHop + kcap + 256;         // 416000
  const size_t xp_bytes  = (size_t)kB * xps * sizeof(_Float16);
  const size_t acc_off   = (xp_bytes + 511) & ~(size_t)511;
  const size_t acc_bytes = (size_t)kAccTotal * sizeof(float);
  const size_t bp_off    = (acc_off + acc_bytes + 511) & ~(size_t)511;

  const double Q = 1.0 / (exp2(1.0 / 24.0) - 1.0);

  // ---- path A job table: slab=1024, 256-aligned support trim ----
  Jobs3 j3;
  int nj3 = 0, totch = 0;
  bool ok3 = true;
  for (int g = 0; g < 11; ++g) {
    const int gk0 = 16 * g;
    const double f0 = 32.7 * exp2((double)gk0 / 24.0);
    const int N = (int)ceil(Q * (double)kSR / f0) + 8;
    int lo_r = nmax - N;
    if (lo_r < 0) lo_r = 0;
    lo_r &= ~255;
    for (int s = lo_r; s < kcap; s += 1024) {
      if (nj3 >= kMaxJobs) { ok3 = false; break; }
      const int hi = (s + 1024 < kcap) ? s + 1024 : kcap;
      j3.k0[nj3]    = gk0;
      j3.lo[nj3]    = s;
      j3.nch[nj3]   = (hi - s) / 32;
      j3.cbase[nj3] = totch;
      j3.sbase[nj3] = totch / 2;
      totch += j3.nch[nj3];
      ++nj3;
    }
    if (!ok3) break;
  }
  j3.n = nj3;              // 66 expected
  j3.totch = totch;        // 1984 expected
  j3.totsp = totch / 2;    // 992

  const size_t bp_bytes = (size_t)totch * 2048;
  const size_t ws_A = bp_off + bp_bytes;      // ~11.7 MB
  const size_t ws_B = acc_off + acc_bytes;

  if (ok3 && ws_size >= ws_A) {
    // ---- path A ----
    _Float16* xp = (_Float16*)d_ws;
    float* accb  = (float*)((char*)d_ws + acc_off);
    _Float16* bp = (_Float16*)((char*)d_ws + bp_off);

    const int nbx = (kB * (xps / 2) + 255) / 256;    // 3250
    const int nbp = j3.totsp * 4;                    // 3968
    const int nba = (kAccTotal / 4 + 255) / 256;     // 1056
    prep_fused<<<nbx + nbp + nba, 256, 0, stream>>>(
        x, kr, ki, xp, bp, accb, pad, xps, nmax, nbx, nbp, j3);

    {
      dim3 grid(nj3, kTPad / 64, kB);   // (66, 12, 4) = 3168 wave-WGs
      cqt_mfma3<<<grid, 64, 0, stream>>>(bp, xp, accb, xps, j3);
    }
    {
      const int total = kB * kT * kBins;
      cqt_mag_final<<<(total + 255) / 256, 256, 0, stream>>>(accb, out);
    }
    return;
  }

  if (ws_size >= ws_B) {
    // ---- path B (round-3, verified ~224us) ----
    _Float16* xp = (_Float16*)d_ws;
    float* accb  = (float*)((char*)d_ws + acc_off);
    Jobs jt;
    int nj = 0;
    for (int g = 0; g < 11; ++g) {
      const int gk0 = 16 * g;
      const double f0 = 32.7 * exp2((double)gk0 / 24.0);
      const int N = (int)ceil(Q * (double)kSR / f0) + 8;
      int lo = nmax - N;
      if (lo < 0) lo = 0;
      lo = (lo / 2048) * 2048;
      for (int s = lo; s < kcap && nj < 48; s += 2048) {
        jt.k0[nj] = gk0;
        jt.lo[nj] = s;
        jt.hi[nj] = (s + 2048 < kcap) ? s + 2048 : kcap;
        ++nj;
      }
    }
    jt.n = nj;
    hipMemsetAsync(accb, 0, acc_bytes, stream);
    {
      const int total = kB * (xps / 2);
      prep_x_kernel<<<(total + 255) / 256, 256, 0, stream>>>(x, xp, pad, xps);
    }
    {
      dim3 grid(nj, kTPad / 256, kB);
      cqt_mfma_kernel<<<grid, 256, 0, stream>>>(kr, ki, xp, accb, nmax, xps, jt);
    }
    {
      const int total = kB * kT * kBins;
      cqt_mag_final<<<(total + 255) / 256, 256, 0, stream>>>(accb, out);
    }
    return;
  }

  // ---- path C: fp32 fallback ----
  {
    const int blocks = fb32::kWaves / 4;
    cqt_mag_kernel<<<blocks, 256, 0, stream>>>(x, kr, ki, out, nmax, pad);
  }
}